// Round 1
// baseline (168.617 us; speedup 1.0000x reference)
//
#include <hip/hip_runtime.h>
#include <hip/hip_bf16.h>

typedef short short8 __attribute__((ext_vector_type(8)));
typedef float f32x4 __attribute__((ext_vector_type(4)));
typedef unsigned short u16;
typedef u16 u16x8 __attribute__((ext_vector_type(8)));

static constexpr float kAlpha = 0.2f;

static __device__ inline u16 f2bf(float f) {
  __hip_bfloat16 h = __float2bfloat16(f);
  return *reinterpret_cast<u16*>(&h);
}
static __device__ inline float bf2f(u16 v) {
  unsigned int u = ((unsigned int)v) << 16;
  return __uint_as_float(u);
}

// ---------------- K1: hbT[b][o][n] = (X @ W)[b][n][o]  (bf16) ----------------
// grid 2048 blocks x 256 thr; each block 8 rows (n) of one batch.
__global__ __launch_bounds__(256) void k1_hW(const float* __restrict__ X,
                                             const float* __restrict__ W,
                                             u16* __restrict__ hbT) {
  int row0 = blockIdx.x * 8;  // global row index over b*4096+n
  int o = threadIdx.x & 127;
  int g = threadIdx.x >> 7;   // 0..1
  __shared__ float Xs[8][128];
#pragma unroll
  for (int s = 0; s < 4; ++s) {
    int idx = threadIdx.x + s * 256;
    Xs[idx >> 7][idx & 127] = X[(size_t)row0 * 128 + idx];
  }
  __syncthreads();
  float acc[4] = {0.f, 0.f, 0.f, 0.f};
  for (int k = 0; k < 128; ++k) {
    float w = W[k * 128 + o];
#pragma unroll
    for (int s = 0; s < 4; ++s) acc[s] += Xs[g + 2 * s][k] * w;
  }
  int b = row0 >> 12;
  int n0 = row0 & 4095;
#pragma unroll
  for (int s = 0; s < 4; ++s)
    hbT[((size_t)b * 128 + o) * 4096 + n0 + g + 2 * s] = f2bf(acc[s]);
}

// ---------------- K1b: f1[b][n] = h.a1, f2[b][n] = h.a2 ----------------
__global__ __launch_bounds__(256) void k1b_f(const u16* __restrict__ hbT,
                                             const float* __restrict__ a1,
                                             const float* __restrict__ a2,
                                             float* __restrict__ f1,
                                             float* __restrict__ f2) {
  int idx = blockIdx.x * 256 + threadIdx.x;  // b*4096+n
  int b = idx >> 12;
  int n = idx & 4095;
  const u16* base = hbT + (size_t)b * 128 * 4096 + n;
  float s1 = 0.f, s2 = 0.f;
  for (int o = 0; o < 128; ++o) {
    float h = bf2f(base[(size_t)o * 4096]);
    s1 += h * a1[o];
    s2 += h * a2[o];
  }
  f1[idx] = s1;
  f2[idx] = s2;
}

// ---------------- K2: partial column sums of exp(adj*e) ----------------
// grid = b(4) * jt(64) * ic(8) = 2048 blocks x 256 thr.
__global__ __launch_bounds__(256) void k2_dpart(const float* __restrict__ adj,
                                                const float* __restrict__ f1,
                                                const float* __restrict__ f2,
                                                float* __restrict__ dpart) {
  int bid = blockIdx.x;
  int ic = bid & 7;
  bid >>= 3;
  int jt = bid & 63;
  int b = bid >> 6;
  int c = threadIdx.x & 63, r = threadIdx.x >> 6;
  int j = jt * 64 + c;
  float f2j = f2[b * 4096 + j];
  const float* arow = adj + ((size_t)b * 4096 + ic * 512 + r) * 4096 + j;
  const float* f1p = f1 + b * 4096 + ic * 512 + r;
  float sum = 0.f;
#pragma unroll 4
  for (int s = 0; s < 128; ++s) {
    float a = arow[(size_t)(4 * s) * 4096];
    float e = f1p[4 * s] + f2j;
    e = e >= 0.f ? e : kAlpha * e;
    sum += __expf(a * e);
  }
  __shared__ float red[256];
  red[threadIdx.x] = sum;
  __syncthreads();
  if (threadIdx.x < 64) {
    float t = red[threadIdx.x] + red[threadIdx.x + 64] + red[threadIdx.x + 128] +
              red[threadIdx.x + 192];
    dpart[(size_t)(b * 8 + ic) * 4096 + j] = t;
  }
}

// ---------------- K2b: rd = 1/sum of partials ----------------
__global__ __launch_bounds__(256) void k2b_rd(const float* __restrict__ dpart,
                                              float* __restrict__ rd) {
  int idx = blockIdx.x * 256 + threadIdx.x;  // 16384
  int b = idx >> 12, j = idx & 4095;
  float s = 0.f;
#pragma unroll
  for (int ic = 0; ic < 8; ++ic) s += dpart[(size_t)(b * 8 + ic) * 4096 + j];
  rd[idx] = 1.0f / s;
}

// ---------------- K3: out = P @ h + bias + input (MFMA bf16) ----------------
// grid 256 blocks (b x 64 row-tiles of 64), 512 thr = 8 waves.
#define LROW 72
__global__ __launch_bounds__(512) void k3_out(
    const float* __restrict__ adj, const u16* __restrict__ hbT,
    const float* __restrict__ f1, const float* __restrict__ f2,
    const float* __restrict__ rd, const float* __restrict__ bias,
    const float* __restrict__ input, float* __restrict__ out) {
  int bid = blockIdx.x;
  int b = bid >> 6;
  int i0 = (bid & 63) * 64;
  int t = threadIdx.x;
  int lane = t & 63;
  int w = t >> 6;

  __shared__ u16 As[64 * LROW];   // P tile [i][j]
  __shared__ u16 Bs[128 * LROW];  // h^T tile [o][j]

  const size_t badj = (size_t)b * 4096 * 4096;
  const float* f1b = f1 + b * 4096;
  const float* f2b = f2 + b * 4096;
  const float* rdb = rd + b * 4096;
  const u16* hb = hbT + (size_t)b * 128 * 4096;

  int ac = t & 63;   // A staging: column offset
  int ar0 = t >> 6;  // A staging: row phase 0..7
  int bj8 = t & 7;   // B staging: 8-elem j chunk
  int bo = t >> 3;   // B staging: o row 0..63

  f32x4 acc[4];
#pragma unroll
  for (int n = 0; n < 4; ++n) acc[n] = (f32x4){0.f, 0.f, 0.f, 0.f};

  int rg = w & 3;   // row group (16 rows)
  int ch = w >> 2;  // column half (64 cols)

  for (int j0 = 0; j0 < 4096; j0 += 64) {
    // ---- stage A: P[i0..i0+63][j0..j0+63] in bf16 ----
    float f2j = f2b[j0 + ac];
    float rdj = rdb[j0 + ac];
#pragma unroll
    for (int s = 0; s < 8; ++s) {
      int r = ar0 + 8 * s;
      float a = adj[badj + (size_t)(i0 + r) * 4096 + j0 + ac];
      float e = f1b[i0 + r] + f2j;
      e = e >= 0.f ? e : kAlpha * e;
      float p = __expf(a * e) * rdj;
      As[r * LROW + ac] = f2bf(p);
    }
    // ---- stage B: Bs[o][j] = hbT[b][o][j0+j] ----
#pragma unroll
    for (int s = 0; s < 2; ++s) {
      int o = bo + 64 * s;
      const u16* src = hb + (size_t)o * 4096 + j0 + bj8 * 8;
      u16x8 v = *reinterpret_cast<const u16x8*>(src);
      *reinterpret_cast<u16x8*>(&Bs[o * LROW + bj8 * 8]) = v;
    }
    __syncthreads();
    // ---- MFMA: acc += P-tile @ h-tile ----
#pragma unroll
    for (int kk = 0; kk < 64; kk += 32) {
      int arow = 16 * rg + (lane & 15);
      int koff = kk + (lane >> 4) * 8;
      short8 af = *reinterpret_cast<const short8*>(&As[arow * LROW + koff]);
#pragma unroll
      for (int n = 0; n < 4; ++n) {
        int brow = 64 * ch + n * 16 + (lane & 15);
        short8 bf = *reinterpret_cast<const short8*>(&Bs[brow * LROW + koff]);
        acc[n] = __builtin_amdgcn_mfma_f32_16x16x32_bf16(af, bf, acc[n], 0, 0, 0);
      }
    }
    __syncthreads();
  }

  // ---- epilogue: + bias + input ----
  int colbase = ch * 64 + (lane & 15);
  int rowbase = i0 + rg * 16 + (lane >> 4) * 4;
#pragma unroll
  for (int n = 0; n < 4; ++n) {
    int o = colbase + n * 16;
#pragma unroll
    for (int q = 0; q < 4; ++q) {
      int i = rowbase + q;
      size_t oidx = ((size_t)b * 4096 + i) * 128 + o;
      out[oidx] = acc[n][q] + bias[i * 128 + o] + input[oidx];
    }
  }
}

extern "C" void kernel_launch(void* const* d_in, const int* in_sizes, int n_in,
                              void* d_out, int out_size, void* d_ws, size_t ws_size,
                              hipStream_t stream) {
  const float* input = (const float*)d_in[0];
  const float* adj = (const float*)d_in[1];
  const float* W = (const float*)d_in[2];
  const float* a1 = (const float*)d_in[3];
  const float* a2 = (const float*)d_in[4];
  const float* bias = (const float*)d_in[5];
  float* out = (float*)d_out;

  char* ws = (char*)d_ws;
  u16* hbT = (u16*)(ws);                       // 4*128*4096*2   = 4,194,304 B
  float* f1 = (float*)(ws + 4194304);          // 4*4096*4      =    65,536 B
  float* f2 = (float*)(ws + 4259840);          // 4*4096*4      =    65,536 B
  float* dpart = (float*)(ws + 4325376);       // 4*8*4096*4    =   524,288 B
  float* rd = (float*)(ws + 4849664);          // 4*4096*4      =    65,536 B

  k1_hW<<<2048, 256, 0, stream>>>(input, W, hbT);
  k1b_f<<<64, 256, 0, stream>>>(hbT, a1, a2, f1, f2);
  k2_dpart<<<2048, 256, 0, stream>>>(adj, f1, f2, dpart);
  k2b_rd<<<64, 256, 0, stream>>>(dpart, rd);
  k3_out<<<256, 512, 0, stream>>>(adj, hbT, f1, f2, rd, bias, input, out);
}

// Round 2
// 152.005 us; speedup vs baseline: 1.1093x; 1.1093x over previous
//
#include <hip/hip_runtime.h>
#include <hip/hip_bf16.h>

typedef short short8 __attribute__((ext_vector_type(8)));
typedef float f32x4 __attribute__((ext_vector_type(4)));
typedef unsigned short u16;
typedef u16 u16x8 __attribute__((ext_vector_type(8)));

static constexpr float kAlpha = 0.2f;

static __device__ inline u16 f2bf(float f) {
  __hip_bfloat16 h = __float2bfloat16(f);
  return *reinterpret_cast<u16*>(&h);
}
static __device__ inline float bf2f(u16 v) {
  unsigned int u = ((unsigned int)v) << 16;
  return __uint_as_float(u);
}

// ---------------- K1: hbT[b][o][n] = (X @ W)[b][n][o]  (bf16) ----------------
__global__ __launch_bounds__(256) void k1_hW(const float* __restrict__ X,
                                             const float* __restrict__ W,
                                             u16* __restrict__ hbT) {
  int row0 = blockIdx.x * 8;  // global row index over b*4096+n
  int o = threadIdx.x & 127;
  int g = threadIdx.x >> 7;   // 0..1
  __shared__ float Xs[8][128];
#pragma unroll
  for (int s = 0; s < 4; ++s) {
    int idx = threadIdx.x + s * 256;
    Xs[idx >> 7][idx & 127] = X[(size_t)row0 * 128 + idx];
  }
  __syncthreads();
  float acc[4] = {0.f, 0.f, 0.f, 0.f};
  for (int k = 0; k < 128; ++k) {
    float w = W[k * 128 + o];
#pragma unroll
    for (int s = 0; s < 4; ++s) acc[s] += Xs[g + 2 * s][k] * w;
  }
  int b = row0 >> 12;
  int n0 = row0 & 4095;
#pragma unroll
  for (int s = 0; s < 4; ++s)
    hbT[((size_t)b * 128 + o) * 4096 + n0 + g + 2 * s] = f2bf(acc[s]);
}

// ---------------- K1b: f1[b][n] = h.a1, f2[b][n] = h.a2 ----------------
__global__ __launch_bounds__(256) void k1b_f(const u16* __restrict__ hbT,
                                             const float* __restrict__ a1,
                                             const float* __restrict__ a2,
                                             float* __restrict__ f1,
                                             float* __restrict__ f2) {
  int idx = blockIdx.x * 256 + threadIdx.x;  // b*4096+n
  int b = idx >> 12;
  int n = idx & 4095;
  const u16* base = hbT + (size_t)b * 128 * 4096 + n;
  float s1 = 0.f, s2 = 0.f;
  for (int o = 0; o < 128; ++o) {
    float h = bf2f(base[(size_t)o * 4096]);
    s1 += h * a1[o];
    s2 += h * a2[o];
  }
  f1[idx] = s1;
  f2[idx] = s2;
}

// ---------------- K2: partial column sums of exp(adj*e), float4 ----------------
// grid = 4b * 16jt * 32ic = 2048 blocks x 256 thr
__global__ __launch_bounds__(256) void k2_dpart(const float* __restrict__ adj,
                                                const float* __restrict__ f1,
                                                const float* __restrict__ f2,
                                                float* __restrict__ dpart) {
  int bid = blockIdx.x;
  int ic = bid & 31;
  int jt = (bid >> 5) & 15;
  int b = bid >> 9;
  int t = threadIdx.x;
  int c = t & 63, r = t >> 6;
  int j = jt * 256 + c * 4;
  const size_t badj = (size_t)b * 4096 * 4096;
  f32x4 f2v = *reinterpret_cast<const f32x4*>(&f2[b * 4096 + j]);
  const float* f1p = f1 + b * 4096;
  int row0 = ic * 128 + r;
  f32x4 sum = (f32x4){0.f, 0.f, 0.f, 0.f};
#pragma unroll 8
  for (int s = 0; s < 32; ++s) {
    int row = row0 + 4 * s;
    f32x4 a = *reinterpret_cast<const f32x4*>(&adj[badj + (size_t)row * 4096 + j]);
    float f1r = f1p[row];
#pragma unroll
    for (int k = 0; k < 4; ++k) {
      float e = f1r + f2v[k];
      e = e >= 0.f ? e : kAlpha * e;
      sum[k] += __expf(a[k] * e);
    }
  }
  __shared__ f32x4 red[256];
  red[t] = sum;
  __syncthreads();
  if (t < 64) {
    f32x4 tt = red[t] + red[t + 64] + red[t + 128] + red[t + 192];
    *reinterpret_cast<f32x4*>(&dpart[(size_t)(b * 32 + ic) * 4096 + j]) = tt;
  }
}

// -------- K2b: rd=1/sum; hs[b][o][j] = hbT[b][o][j] * rd[b][j] (bf16) --------
__global__ __launch_bounds__(256) void k2b_scale(const float* __restrict__ dpart,
                                                 const u16* __restrict__ hbT,
                                                 u16* __restrict__ hs) {
  int idx = blockIdx.x * 256 + threadIdx.x;  // 16384 = b*4096+j
  int b = idx >> 12, j = idx & 4095;
  float s = 0.f;
#pragma unroll
  for (int ic = 0; ic < 32; ++ic) s += dpart[(size_t)(b * 32 + ic) * 4096 + j];
  float rd = 1.0f / s;
  const u16* src = hbT + (size_t)b * 128 * 4096 + j;
  u16* dst = hs + (size_t)b * 128 * 4096 + j;
#pragma unroll 4
  for (int o = 0; o < 128; ++o) {
    dst[(size_t)o * 4096] = f2bf(bf2f(src[(size_t)o * 4096]) * rd);
  }
}

// ---------------- K3: out = P @ hs + bias + input (MFMA bf16) ----------------
// grid 256 blocks (b x 64 row-tiles of 64), 512 thr = 8 waves.
// Double-buffered LDS, register prefetch one tile ahead, 1 barrier/tile.
#define LROW 72
__global__ __launch_bounds__(512) void k3_out(
    const float* __restrict__ adj, const u16* __restrict__ hs,
    const float* __restrict__ f1, const float* __restrict__ f2,
    const float* __restrict__ bias, const float* __restrict__ input,
    float* __restrict__ out) {
  int bid = blockIdx.x;
  int b = bid >> 6;
  int i0 = (bid & 63) * 64;
  int t = threadIdx.x;
  int lane = t & 63;
  int w = t >> 6;

  __shared__ u16 As[2][64 * LROW];
  __shared__ u16 Bs[2][128 * LROW];
  __shared__ float f2s[4096];

  const size_t badj = (size_t)b * 4096 * 4096;
  const u16* hb = hs + (size_t)b * 128 * 4096;

  // stage f2 row for this batch into LDS (16 KB)
  {
    const f32x4* src = reinterpret_cast<const f32x4*>(f2 + b * 4096);
    f32x4* dst = reinterpret_cast<f32x4*>(f2s);
    dst[t] = src[t];
    dst[t + 512] = src[t + 512];
  }

  // A staging map: thread covers row rr, cols c0..c0+7 of the 64x64 adj tile
  int rr = t >> 3;          // 0..63
  int c0 = (t & 7) * 8;     // 0..56
  // B staging map: thread covers o=bo, 16 cols starting bc0
  int bo = t >> 2;          // 0..127
  int bc0 = (t & 3) * 16;   // 0..48

  float f1v = f1[b * 4096 + i0 + rr];

  f32x4 acc[4];
#pragma unroll
  for (int n = 0; n < 4; ++n) acc[n] = (f32x4){0.f, 0.f, 0.f, 0.f};

  int rg = w & 3;   // row group (16 rows)
  int ch = w >> 2;  // column half of o (64)

  // prefetch register sets A/B (static names; no runtime indexing)
  f32x4 raA0, raA1, raB0, raB1;
  u16x8 rbA0, rbA1, rbB0, rbB1;

#define PREFETCH(S, J0)                                                              \
  {                                                                                  \
    const f32x4* ap = reinterpret_cast<const f32x4*>(                                \
        adj + badj + (size_t)(i0 + rr) * 4096 + (J0) + c0);                          \
    ra##S##0 = ap[0];                                                                \
    ra##S##1 = ap[1];                                                                \
    const u16x8* bp =                                                                \
        reinterpret_cast<const u16x8*>(hb + (size_t)bo * 4096 + (J0) + bc0);         \
    rb##S##0 = bp[0];                                                                \
    rb##S##1 = bp[1];                                                                \
  }

#define STORE(S, J0, BUF)                                                            \
  {                                                                                  \
    f32x4 e0 = *reinterpret_cast<const f32x4*>(&f2s[(J0) + c0]);                     \
    f32x4 e1 = *reinterpret_cast<const f32x4*>(&f2s[(J0) + c0 + 4]);                 \
    u16x8 pv;                                                                        \
    _Pragma("unroll") for (int k = 0; k < 4; ++k) {                                  \
      float e = f1v + e0[k];                                                         \
      e = e >= 0.f ? e : kAlpha * e;                                                 \
      pv[k] = f2bf(__expf(ra##S##0[k] * e));                                         \
    }                                                                                \
    _Pragma("unroll") for (int k = 0; k < 4; ++k) {                                  \
      float e = f1v + e1[k];                                                         \
      e = e >= 0.f ? e : kAlpha * e;                                                 \
      pv[k + 4] = f2bf(__expf(ra##S##1[k] * e));                                     \
    }                                                                                \
    *reinterpret_cast<u16x8*>(&As[BUF][rr * LROW + c0]) = pv;                        \
    *reinterpret_cast<u16x8*>(&Bs[BUF][bo * LROW + bc0]) = rb##S##0;                 \
    *reinterpret_cast<u16x8*>(&Bs[BUF][bo * LROW + bc0 + 8]) = rb##S##1;             \
  }

#define DOMFMA(BUF)                                                                  \
  {                                                                                  \
    _Pragma("unroll") for (int kk = 0; kk < 64; kk += 32) {                          \
      short8 af = *reinterpret_cast<const short8*>(                                  \
          &As[BUF][(16 * rg + (lane & 15)) * LROW + kk + (lane >> 4) * 8]);          \
      _Pragma("unroll") for (int n = 0; n < 4; ++n) {                                \
        short8 bf = *reinterpret_cast<const short8*>(                                \
            &Bs[BUF][(64 * ch + n * 16 + (lane & 15)) * LROW + kk +                  \
                     (lane >> 4) * 8]);                                              \
        acc[n] = __builtin_amdgcn_mfma_f32_16x16x32_bf16(af, bf, acc[n], 0, 0, 0);   \
      }                                                                              \
    }                                                                                \
  }

  PREFETCH(A, 0);
  __syncthreads();  // f2s visible (also orders nothing else yet)

  for (int j0 = 0; j0 < 4096; j0 += 128) {
    PREFETCH(B, j0 + 64);       // issue next-tile loads early
    STORE(A, j0, 0);            // exp + ds_write current tile
    __syncthreads();            // buf0 ready
    DOMFMA(0);
    if (j0 + 128 < 4096) PREFETCH(A, j0 + 128);
    STORE(B, j0 + 64, 1);
    __syncthreads();            // buf1 ready
    DOMFMA(1);
  }

  // ---- epilogue: + bias + input ----
  int colbase = ch * 64 + (lane & 15);
  int rowbase = i0 + rg * 16 + (lane >> 4) * 4;
#pragma unroll
  for (int n = 0; n < 4; ++n) {
    int o = colbase + n * 16;
#pragma unroll
    for (int q = 0; q < 4; ++q) {
      int i = rowbase + q;
      size_t oidx = ((size_t)b * 4096 + i) * 128 + o;
      out[oidx] = acc[n][q] + bias[i * 128 + o] + input[oidx];
    }
  }
}

extern "C" void kernel_launch(void* const* d_in, const int* in_sizes, int n_in,
                              void* d_out, int out_size, void* d_ws, size_t ws_size,
                              hipStream_t stream) {
  const float* input = (const float*)d_in[0];
  const float* adj = (const float*)d_in[1];
  const float* W = (const float*)d_in[2];
  const float* a1 = (const float*)d_in[3];
  const float* a2 = (const float*)d_in[4];
  const float* bias = (const float*)d_in[5];
  float* out = (float*)d_out;

  char* ws = (char*)d_ws;
  u16* hbT = (u16*)(ws);                  // 4*128*4096*2 = 4,194,304 B
  float* f1 = (float*)(ws + 4194304);     // 65,536 B
  float* f2 = (float*)(ws + 4259840);     // 65,536 B
  float* dpart = (float*)(ws + 4325376);  // 4*32*4096*4 = 2,097,152 B
  u16* hs = (u16*)(ws + 6422528);         // 4,194,304 B

  k1_hW<<<2048, 256, 0, stream>>>(input, W, hbT);
  k1b_f<<<64, 256, 0, stream>>>(hbT, a1, a2, f1, f2);
  k2_dpart<<<2048, 256, 0, stream>>>(adj, f1, f2, dpart);
  k2b_scale<<<64, 256, 0, stream>>>(dpart, hbT, hs);
  k3_out<<<256, 512, 0, stream>>>(adj, hs, f1, f2, bias, input, out);
}

// Round 3
// 142.299 us; speedup vs baseline: 1.1849x; 1.0682x over previous
//
#include <hip/hip_runtime.h>
#include <hip/hip_bf16.h>

typedef short short8 __attribute__((ext_vector_type(8)));
typedef float f32x4 __attribute__((ext_vector_type(4)));
typedef unsigned short u16;
typedef u16 u16x8 __attribute__((ext_vector_type(8)));

static constexpr float kAlpha = 0.2f;

static __device__ inline u16 f2bf(float f) {
  __hip_bfloat16 h = __float2bfloat16(f);
  return *reinterpret_cast<u16*>(&h);
}
static __device__ inline float bf2f(u16 v) {
  unsigned int u = ((unsigned int)v) << 16;
  return __uint_as_float(u);
}

// ---------------- K1: hbT[b][o][n] = (X @ W)[b][n][o]  (bf16) ----------------
__global__ __launch_bounds__(256) void k1_hW(const float* __restrict__ X,
                                             const float* __restrict__ W,
                                             u16* __restrict__ hbT) {
  int row0 = blockIdx.x * 8;  // global row index over b*4096+n
  int o = threadIdx.x & 127;
  int g = threadIdx.x >> 7;   // 0..1
  __shared__ float Xs[8][128];
#pragma unroll
  for (int s = 0; s < 4; ++s) {
    int idx = threadIdx.x + s * 256;
    Xs[idx >> 7][idx & 127] = X[(size_t)row0 * 128 + idx];
  }
  __syncthreads();
  float acc[4] = {0.f, 0.f, 0.f, 0.f};
  for (int k = 0; k < 128; ++k) {
    float w = W[k * 128 + o];
#pragma unroll
    for (int s = 0; s < 4; ++s) acc[s] += Xs[g + 2 * s][k] * w;
  }
  int b = row0 >> 12;
  int n0 = row0 & 4095;
#pragma unroll
  for (int s = 0; s < 4; ++s)
    hbT[((size_t)b * 128 + o) * 4096 + n0 + g + 2 * s] = f2bf(acc[s]);
}

// ---------------- K1b: f1[b][n] = h.a1, f2[b][n] = h.a2 ----------------
__global__ __launch_bounds__(256) void k1b_f(const u16* __restrict__ hbT,
                                             const float* __restrict__ a1,
                                             const float* __restrict__ a2,
                                             float* __restrict__ f1,
                                             float* __restrict__ f2) {
  int idx = blockIdx.x * 256 + threadIdx.x;  // b*4096+n
  int b = idx >> 12;
  int n = idx & 4095;
  const u16* base = hbT + (size_t)b * 128 * 4096 + n;
  float s1 = 0.f, s2 = 0.f;
  for (int o = 0; o < 128; ++o) {
    float h = bf2f(base[(size_t)o * 4096]);
    s1 += h * a1[o];
    s2 += h * a2[o];
  }
  f1[idx] = s1;
  f2[idx] = s2;
}

// ---------------- K2: partial column sums of exp(adj*e), float4 ----------------
// grid = 4b * 16jt * 32ic = 2048 blocks x 256 thr
__global__ __launch_bounds__(256) void k2_dpart(const float* __restrict__ adj,
                                                const float* __restrict__ f1,
                                                const float* __restrict__ f2,
                                                float* __restrict__ dpart) {
  int bid = blockIdx.x;
  int ic = bid & 31;
  int jt = (bid >> 5) & 15;
  int b = bid >> 9;
  int t = threadIdx.x;
  int c = t & 63, r = t >> 6;
  int j = jt * 256 + c * 4;
  const size_t badj = (size_t)b * 4096 * 4096;
  f32x4 f2v = *reinterpret_cast<const f32x4*>(&f2[b * 4096 + j]);
  const float* f1p = f1 + b * 4096;
  int row0 = ic * 128 + r;
  f32x4 sum = (f32x4){0.f, 0.f, 0.f, 0.f};
#pragma unroll 8
  for (int s = 0; s < 32; ++s) {
    int row = row0 + 4 * s;
    f32x4 a = *reinterpret_cast<const f32x4*>(&adj[badj + (size_t)row * 4096 + j]);
    float f1r = f1p[row];
#pragma unroll
    for (int k = 0; k < 4; ++k) {
      float e = f1r + f2v[k];
      e = e >= 0.f ? e : kAlpha * e;
      sum[k] += __expf(a[k] * e);
    }
  }
  __shared__ f32x4 red[256];
  red[t] = sum;
  __syncthreads();
  if (t < 64) {
    f32x4 tt = red[t] + red[t + 64] + red[t + 128] + red[t + 192];
    *reinterpret_cast<f32x4*>(&dpart[(size_t)(b * 32 + ic) * 4096 + j]) = tt;
  }
}

// -------- K2b: rd=1/sum; hs[b][o][j] = hbT[b][o][j] * rd[b][j] (bf16) --------
__global__ __launch_bounds__(256) void k2b_scale(const float* __restrict__ dpart,
                                                 const u16* __restrict__ hbT,
                                                 u16* __restrict__ hs) {
  int idx = blockIdx.x * 256 + threadIdx.x;  // 16384 = b*4096+j
  int b = idx >> 12, j = idx & 4095;
  float s = 0.f;
#pragma unroll
  for (int ic = 0; ic < 32; ++ic) s += dpart[(size_t)(b * 32 + ic) * 4096 + j];
  float rd = 1.0f / s;
  const u16* src = hbT + (size_t)b * 128 * 4096 + j;
  u16* dst = hs + (size_t)b * 128 * 4096 + j;
#pragma unroll 4
  for (int o = 0; o < 128; ++o) {
    dst[(size_t)o * 4096] = f2bf(bf2f(src[(size_t)o * 4096]) * rd);
  }
}

// ---------------- K3: out = P @ hs + bias + input (MFMA bf16) ----------------
// grid 256 blocks (b x 64 row-tiles of 64), 512 thr = 8 waves.
// Depth-4-phase register prefetch pipeline + double-buffered LDS,
// 1 barrier per 64-tile. Prefetch->use distance ~3 phases (>1500 cy).
#define LROW 72
__global__ __launch_bounds__(512) void k3_out(
    const float* __restrict__ adj, const u16* __restrict__ hs,
    const float* __restrict__ f1, const float* __restrict__ f2,
    const float* __restrict__ bias, const float* __restrict__ input,
    float* __restrict__ out) {
  int bid = blockIdx.x;
  int b = bid >> 6;
  int i0 = (bid & 63) * 64;
  int t = threadIdx.x;
  int lane = t & 63;
  int w = t >> 6;

  __shared__ u16 As[2][64 * LROW];
  __shared__ u16 Bs[2][128 * LROW];
  __shared__ float f2s[4096];

  const size_t badj = (size_t)b * 4096 * 4096;
  const u16* hb = hs + (size_t)b * 128 * 4096;

  // stage f2 row for this batch into LDS (16 KB)
  {
    const f32x4* src = reinterpret_cast<const f32x4*>(f2 + b * 4096);
    f32x4* dst = reinterpret_cast<f32x4*>(f2s);
    dst[t] = src[t];
    dst[t + 512] = src[t + 512];
  }

  // A staging map: thread covers row rr, cols c0..c0+7 of the 64x64 adj tile
  int rr = t >> 3;          // 0..63
  int c0 = (t & 7) * 8;     // 0..56
  // B staging map: thread covers o=bo, 16 cols starting bc0
  int bo = t >> 2;          // 0..127
  int bc0 = (t & 3) * 16;   // 0..48

  float f1v = f1[b * 4096 + i0 + rr];

  f32x4 acc[4];
#pragma unroll
  for (int n = 0; n < 4; ++n) acc[n] = (f32x4){0.f, 0.f, 0.f, 0.f};

  int rg = w & 3;   // row group (16 rows)
  int ch = w >> 2;  // column half of o (64)

  // 4 named prefetch register sets (static indexing only)
  f32x4 raA0, raA1, raB0, raB1, raC0, raC1, raD0, raD1;
  u16x8 rbA0, rbA1, rbB0, rbB1, rbC0, rbC1, rbD0, rbD1;

#define PREFETCH(S, J0)                                                              \
  {                                                                                  \
    int jj = (J0) & 4095; /* tail prefetches wrap to valid memory, unused */         \
    const f32x4* ap = reinterpret_cast<const f32x4*>(                                \
        adj + badj + (size_t)(i0 + rr) * 4096 + jj + c0);                            \
    ra##S##0 = ap[0];                                                                \
    ra##S##1 = ap[1];                                                                \
    const u16x8* bp =                                                                \
        reinterpret_cast<const u16x8*>(hb + (size_t)bo * 4096 + jj + bc0);           \
    rb##S##0 = bp[0];                                                                \
    rb##S##1 = bp[1];                                                                \
  }

#define STORE(S, J0, BUF)                                                            \
  {                                                                                  \
    f32x4 e0 = *reinterpret_cast<const f32x4*>(&f2s[(J0) + c0]);                     \
    f32x4 e1 = *reinterpret_cast<const f32x4*>(&f2s[(J0) + c0 + 4]);                 \
    u16x8 pv;                                                                        \
    _Pragma("unroll") for (int k = 0; k < 4; ++k) {                                  \
      float e = f1v + e0[k];                                                         \
      e = e >= 0.f ? e : kAlpha * e;                                                 \
      pv[k] = f2bf(__expf(ra##S##0[k] * e));                                         \
    }                                                                                \
    _Pragma("unroll") for (int k = 0; k < 4; ++k) {                                  \
      float e = f1v + e1[k];                                                         \
      e = e >= 0.f ? e : kAlpha * e;                                                 \
      pv[k + 4] = f2bf(__expf(ra##S##1[k] * e));                                     \
    }                                                                                \
    *reinterpret_cast<u16x8*>(&As[BUF][rr * LROW + c0]) = pv;                        \
    *reinterpret_cast<u16x8*>(&Bs[BUF][bo * LROW + bc0]) = rb##S##0;                 \
    *reinterpret_cast<u16x8*>(&Bs[BUF][bo * LROW + bc0 + 8]) = rb##S##1;             \
  }

#define DOMFMA(BUF)                                                                  \
  {                                                                                  \
    _Pragma("unroll") for (int kk = 0; kk < 64; kk += 32) {                          \
      short8 af = *reinterpret_cast<const short8*>(                                  \
          &As[BUF][(16 * rg + (lane & 15)) * LROW + kk + (lane >> 4) * 8]);          \
      _Pragma("unroll") for (int n = 0; n < 4; ++n) {                                \
        short8 bf = *reinterpret_cast<const short8*>(                                \
            &Bs[BUF][(64 * ch + n * 16 + (lane & 15)) * LROW + kk +                  \
                     (lane >> 4) * 8]);                                              \
        acc[n] = __builtin_amdgcn_mfma_f32_16x16x32_bf16(af, bf, acc[n], 0, 0, 0);   \
      }                                                                              \
    }                                                                                \
  }

  // Prologue: fill the 4-deep pipeline.
  PREFETCH(A, 0);
  PREFETCH(B, 64);
  PREFETCH(C, 128);
  PREFETCH(D, 192);
  __syncthreads();  // f2s visible

  for (int j0 = 0; j0 < 4096; j0 += 256) {
    STORE(A, j0, 0);
    __syncthreads();
    DOMFMA(0);
    PREFETCH(A, j0 + 256);
    STORE(B, j0 + 64, 1);
    __syncthreads();
    DOMFMA(1);
    PREFETCH(B, j0 + 320);
    STORE(C, j0 + 128, 0);
    __syncthreads();
    DOMFMA(0);
    PREFETCH(C, j0 + 384);
    STORE(D, j0 + 192, 1);
    __syncthreads();
    DOMFMA(1);
    PREFETCH(D, j0 + 448);
  }

  // ---- epilogue: + bias + input ----
  int colbase = ch * 64 + (lane & 15);
  int rowbase = i0 + rg * 16 + (lane >> 4) * 4;
#pragma unroll
  for (int n = 0; n < 4; ++n) {
    int o = colbase + n * 16;
#pragma unroll
    for (int q = 0; q < 4; ++q) {
      int i = rowbase + q;
      size_t oidx = ((size_t)b * 4096 + i) * 128 + o;
      out[oidx] = acc[n][q] + bias[i * 128 + o] + input[oidx];
    }
  }
}

extern "C" void kernel_launch(void* const* d_in, const int* in_sizes, int n_in,
                              void* d_out, int out_size, void* d_ws, size_t ws_size,
                              hipStream_t stream) {
  const float* input = (const float*)d_in[0];
  const float* adj = (const float*)d_in[1];
  const float* W = (const float*)d_in[2];
  const float* a1 = (const float*)d_in[3];
  const float* a2 = (const float*)d_in[4];
  const float* bias = (const float*)d_in[5];
  float* out = (float*)d_out;

  char* ws = (char*)d_ws;
  u16* hbT = (u16*)(ws);                  // 4*128*4096*2 = 4,194,304 B
  float* f1 = (float*)(ws + 4194304);     // 65,536 B
  float* f2 = (float*)(ws + 4259840);     // 65,536 B
  float* dpart = (float*)(ws + 4325376);  // 4*32*4096*4 = 2,097,152 B
  u16* hs = (u16*)(ws + 6422528);         // 4,194,304 B

  k1_hW<<<2048, 256, 0, stream>>>(input, W, hbT);
  k1b_f<<<64, 256, 0, stream>>>(hbT, a1, a2, f1, f2);
  k2_dpart<<<2048, 256, 0, stream>>>(adj, f1, f2, dpart);
  k2b_scale<<<64, 256, 0, stream>>>(dpart, hbT, hs);
  k3_out<<<256, 512, 0, stream>>>(adj, hs, f1, f2, bias, input, out);
}

// Round 4
// 141.512 us; speedup vs baseline: 1.1915x; 1.0056x over previous
//
#include <hip/hip_runtime.h>
#include <hip/hip_bf16.h>

typedef short short8 __attribute__((ext_vector_type(8)));
typedef float f32x4 __attribute__((ext_vector_type(4)));
typedef unsigned short u16;
typedef u16 u16x8 __attribute__((ext_vector_type(8)));

static constexpr float kAlpha = 0.2f;

static __device__ inline u16 f2bf(float f) {
  __hip_bfloat16 h = __float2bfloat16(f);
  return *reinterpret_cast<u16*>(&h);
}
static __device__ inline float bf2f(u16 v) {
  unsigned int u = ((unsigned int)v) << 16;
  return __uint_as_float(u);
}

// ---------------- K1: hbT[b][o][n] = (X @ W)[b][n][o]  (bf16) ----------------
__global__ __launch_bounds__(256) void k1_hW(const float* __restrict__ X,
                                             const float* __restrict__ W,
                                             u16* __restrict__ hbT) {
  int row0 = blockIdx.x * 8;  // global row index over b*4096+n
  int o = threadIdx.x & 127;
  int g = threadIdx.x >> 7;   // 0..1
  __shared__ float Xs[8][128];
#pragma unroll
  for (int s = 0; s < 4; ++s) {
    int idx = threadIdx.x + s * 256;
    Xs[idx >> 7][idx & 127] = X[(size_t)row0 * 128 + idx];
  }
  __syncthreads();
  float acc[4] = {0.f, 0.f, 0.f, 0.f};
  for (int k = 0; k < 128; ++k) {
    float w = W[k * 128 + o];
#pragma unroll
    for (int s = 0; s < 4; ++s) acc[s] += Xs[g + 2 * s][k] * w;
  }
  int b = row0 >> 12;
  int n0 = row0 & 4095;
#pragma unroll
  for (int s = 0; s < 4; ++s)
    hbT[((size_t)b * 128 + o) * 4096 + n0 + g + 2 * s] = f2bf(acc[s]);
}

// ---------------- K1b: f1[b][n] = h.a1, f2[b][n] = h.a2 ----------------
__global__ __launch_bounds__(256) void k1b_f(const u16* __restrict__ hbT,
                                             const float* __restrict__ a1,
                                             const float* __restrict__ a2,
                                             float* __restrict__ f1,
                                             float* __restrict__ f2) {
  int idx = blockIdx.x * 256 + threadIdx.x;  // b*4096+n
  int b = idx >> 12;
  int n = idx & 4095;
  const u16* base = hbT + (size_t)b * 128 * 4096 + n;
  float s1 = 0.f, s2 = 0.f;
  for (int o = 0; o < 128; ++o) {
    float h = bf2f(base[(size_t)o * 4096]);
    s1 += h * a1[o];
    s2 += h * a2[o];
  }
  f1[idx] = s1;
  f2[idx] = s2;
}

// ---------------- K2: partial column sums of exp(adj*e), float4 ----------------
// grid = 4b * 16jt * 32ic = 2048 blocks x 256 thr
__global__ __launch_bounds__(256) void k2_dpart(const float* __restrict__ adj,
                                                const float* __restrict__ f1,
                                                const float* __restrict__ f2,
                                                float* __restrict__ dpart) {
  int bid = blockIdx.x;
  int ic = bid & 31;
  int jt = (bid >> 5) & 15;
  int b = bid >> 9;
  int t = threadIdx.x;
  int c = t & 63, r = t >> 6;
  int j = jt * 256 + c * 4;
  const size_t badj = (size_t)b * 4096 * 4096;
  f32x4 f2v = *reinterpret_cast<const f32x4*>(&f2[b * 4096 + j]);
  const float* f1p = f1 + b * 4096;
  int row0 = ic * 128 + r;
  f32x4 sum = (f32x4){0.f, 0.f, 0.f, 0.f};
#pragma unroll 8
  for (int s = 0; s < 32; ++s) {
    int row = row0 + 4 * s;
    f32x4 a = *reinterpret_cast<const f32x4*>(&adj[badj + (size_t)row * 4096 + j]);
    float f1r = f1p[row];
#pragma unroll
    for (int k = 0; k < 4; ++k) {
      float e = f1r + f2v[k];
      e = e >= 0.f ? e : kAlpha * e;
      sum[k] += __expf(a[k] * e);
    }
  }
  __shared__ f32x4 red[256];
  red[t] = sum;
  __syncthreads();
  if (t < 64) {
    f32x4 tt = red[t] + red[t + 64] + red[t + 128] + red[t + 192];
    *reinterpret_cast<f32x4*>(&dpart[(size_t)(b * 32 + ic) * 4096 + j]) = tt;
  }
}

// -------- K2b: rd=1/sum; hs[b][o][j] = hbT[b][o][j] * rd[b][j] (bf16) --------
__global__ __launch_bounds__(256) void k2b_scale(const float* __restrict__ dpart,
                                                 const u16* __restrict__ hbT,
                                                 u16* __restrict__ hs) {
  int idx = blockIdx.x * 256 + threadIdx.x;  // 16384 = b*4096+j
  int b = idx >> 12, j = idx & 4095;
  float s = 0.f;
#pragma unroll
  for (int ic = 0; ic < 32; ++ic) s += dpart[(size_t)(b * 32 + ic) * 4096 + j];
  float rd = 1.0f / s;
  const u16* src = hbT + (size_t)b * 128 * 4096 + j;
  u16* dst = hs + (size_t)b * 128 * 4096 + j;
#pragma unroll 4
  for (int o = 0; o < 128; ++o) {
    dst[(size_t)o * 4096] = f2bf(bf2f(src[(size_t)o * 4096]) * rd);
  }
}

// ---------------- K3: out = P @ hs + bias + input (MFMA bf16) ----------------
// grid 256 blocks (b x 64 row-tiles of 64), 512 thr = 8 waves.
// Depth-4-phase register prefetch pipeline + double-buffered LDS.
// Raw s_barrier + lgkmcnt(0)-only (NO vmcnt drain) so prefetches stay in
// flight across barriers (T3/T4; avoids __syncthreads' vmcnt(0) drain).
#define LROW 72
#define BARRIER()                                     \
  {                                                   \
    asm volatile("s_waitcnt lgkmcnt(0)" ::: "memory"); \
    __builtin_amdgcn_s_barrier();                     \
  }
__global__ __launch_bounds__(512) void k3_out(
    const float* __restrict__ adj, const u16* __restrict__ hs,
    const float* __restrict__ f1, const float* __restrict__ f2,
    const float* __restrict__ bias, const float* __restrict__ input,
    float* __restrict__ out) {
  int bid = blockIdx.x;
  int b = bid >> 6;
  int i0 = (bid & 63) * 64;
  int t = threadIdx.x;
  int lane = t & 63;
  int w = t >> 6;

  __shared__ u16 As[2][64 * LROW];
  __shared__ u16 Bs[2][128 * LROW];
  __shared__ float f2s[4096];

  const size_t badj = (size_t)b * 4096 * 4096;
  const u16* hb = hs + (size_t)b * 128 * 4096;

  // stage f2 row for this batch into LDS (16 KB)
  {
    const f32x4* src = reinterpret_cast<const f32x4*>(f2 + b * 4096);
    f32x4* dst = reinterpret_cast<f32x4*>(f2s);
    dst[t] = src[t];
    dst[t + 512] = src[t + 512];
  }
  __syncthreads();  // f2s visible; nothing else in flight yet

  // A staging map: thread covers row rr, cols c0..c0+7 of the 64x64 adj tile
  int rr = t >> 3;          // 0..63
  int c0 = (t & 7) * 8;     // 0..56
  // B staging map: thread covers o=bo, 16 cols starting bc0
  int bo = t >> 2;          // 0..127
  int bc0 = (t & 3) * 16;   // 0..48

  float f1v = f1[b * 4096 + i0 + rr];

  f32x4 acc[4];
#pragma unroll
  for (int n = 0; n < 4; ++n) acc[n] = (f32x4){0.f, 0.f, 0.f, 0.f};

  int rg = w & 3;   // row group (16 rows)
  int ch = w >> 2;  // column half of o (64)

  // 4 named prefetch register sets (static indexing only)
  f32x4 raA0, raA1, raB0, raB1, raC0, raC1, raD0, raD1;
  u16x8 rbA0, rbA1, rbB0, rbB1, rbC0, rbC1, rbD0, rbD1;

#define PREFETCH(S, J0)                                                              \
  {                                                                                  \
    int jj = (J0) & 4095; /* tail prefetches wrap to valid memory, unused */         \
    const f32x4* ap = reinterpret_cast<const f32x4*>(                                \
        adj + badj + (size_t)(i0 + rr) * 4096 + jj + c0);                            \
    ra##S##0 = ap[0];                                                                \
    ra##S##1 = ap[1];                                                                \
    const u16x8* bp =                                                                \
        reinterpret_cast<const u16x8*>(hb + (size_t)bo * 4096 + jj + bc0);           \
    rb##S##0 = bp[0];                                                                \
    rb##S##1 = bp[1];                                                                \
  }

#define STORE(S, J0, BUF)                                                            \
  {                                                                                  \
    f32x4 e0 = *reinterpret_cast<const f32x4*>(&f2s[(J0) + c0]);                     \
    f32x4 e1 = *reinterpret_cast<const f32x4*>(&f2s[(J0) + c0 + 4]);                 \
    u16x8 pv;                                                                        \
    _Pragma("unroll") for (int k = 0; k < 4; ++k) {                                  \
      float e = f1v + e0[k];                                                         \
      e = e >= 0.f ? e : kAlpha * e;                                                 \
      pv[k] = f2bf(__expf(ra##S##0[k] * e));                                         \
    }                                                                                \
    _Pragma("unroll") for (int k = 0; k < 4; ++k) {                                  \
      float e = f1v + e1[k];                                                         \
      e = e >= 0.f ? e : kAlpha * e;                                                 \
      pv[k + 4] = f2bf(__expf(ra##S##1[k] * e));                                     \
    }                                                                                \
    *reinterpret_cast<u16x8*>(&As[BUF][rr * LROW + c0]) = pv;                        \
    *reinterpret_cast<u16x8*>(&Bs[BUF][bo * LROW + bc0]) = rb##S##0;                 \
    *reinterpret_cast<u16x8*>(&Bs[BUF][bo * LROW + bc0 + 8]) = rb##S##1;             \
  }

#define DOMFMA(BUF)                                                                  \
  {                                                                                  \
    _Pragma("unroll") for (int kk = 0; kk < 64; kk += 32) {                          \
      short8 af = *reinterpret_cast<const short8*>(                                  \
          &As[BUF][(16 * rg + (lane & 15)) * LROW + kk + (lane >> 4) * 8]);          \
      _Pragma("unroll") for (int n = 0; n < 4; ++n) {                                \
        short8 bf = *reinterpret_cast<const short8*>(                                \
            &Bs[BUF][(64 * ch + n * 16 + (lane & 15)) * LROW + kk +                  \
                     (lane >> 4) * 8]);                                              \
        acc[n] = __builtin_amdgcn_mfma_f32_16x16x32_bf16(af, bf, acc[n], 0, 0, 0);   \
      }                                                                              \
    }                                                                                \
  }

  // Prologue: fill the 4-deep pipeline (after the f2s sync so nothing drains).
  PREFETCH(A, 0);
  PREFETCH(B, 64);
  PREFETCH(C, 128);
  PREFETCH(D, 192);

  for (int j0 = 0; j0 < 4096; j0 += 256) {
    STORE(A, j0, 0);
    BARRIER();
    DOMFMA(0);
    PREFETCH(A, j0 + 256);
    STORE(B, j0 + 64, 1);
    BARRIER();
    DOMFMA(1);
    PREFETCH(B, j0 + 320);
    STORE(C, j0 + 128, 0);
    BARRIER();
    DOMFMA(0);
    PREFETCH(C, j0 + 384);
    STORE(D, j0 + 192, 1);
    BARRIER();
    DOMFMA(1);
    PREFETCH(D, j0 + 448);
  }

  // ---- epilogue: + bias + input ----
  int colbase = ch * 64 + (lane & 15);
  int rowbase = i0 + rg * 16 + (lane >> 4) * 4;
#pragma unroll
  for (int n = 0; n < 4; ++n) {
    int o = colbase + n * 16;
#pragma unroll
    for (int q = 0; q < 4; ++q) {
      int i = rowbase + q;
      size_t oidx = ((size_t)b * 4096 + i) * 128 + o;
      out[oidx] = acc[n][q] + bias[i * 128 + o] + input[oidx];
    }
  }
}

extern "C" void kernel_launch(void* const* d_in, const int* in_sizes, int n_in,
                              void* d_out, int out_size, void* d_ws, size_t ws_size,
                              hipStream_t stream) {
  const float* input = (const float*)d_in[0];
  const float* adj = (const float*)d_in[1];
  const float* W = (const float*)d_in[2];
  const float* a1 = (const float*)d_in[3];
  const float* a2 = (const float*)d_in[4];
  const float* bias = (const float*)d_in[5];
  float* out = (float*)d_out;

  char* ws = (char*)d_ws;
  u16* hbT = (u16*)(ws);                  // 4*128*4096*2 = 4,194,304 B
  float* f1 = (float*)(ws + 4194304);     // 65,536 B
  float* f2 = (float*)(ws + 4259840);     // 65,536 B
  float* dpart = (float*)(ws + 4325376);  // 4*32*4096*4 = 2,097,152 B
  u16* hs = (u16*)(ws + 6422528);         // 4,194,304 B

  k1_hW<<<2048, 256, 0, stream>>>(input, W, hbT);
  k1b_f<<<64, 256, 0, stream>>>(hbT, a1, a2, f1, f2);
  k2_dpart<<<2048, 256, 0, stream>>>(adj, f1, f2, dpart);
  k2b_scale<<<64, 256, 0, stream>>>(dpart, hbT, hs);
  k3_out<<<256, 512, 0, stream>>>(adj, hs, f1, f2, bias, input, out);
}